// Round 5
// baseline (234.110 us; speedup 1.0000x reference)
//
#include <hip/hip_runtime.h>
#include <hip/hip_bf16.h>

typedef __bf16 bf16x8 __attribute__((ext_vector_type(8)));
typedef float f32x4 __attribute__((ext_vector_type(4)));

#define BATCH 65536
#define NL 256    // N_LSTM
#define NZ 1024   // 4*N_LSTM
#define FEAT 5
#define ROWS 32   // batch rows per tile
#define KTOT 288  // 256 (h@U) + 32 (x@W folded: 5 real + 27 zero)
#define ASTRIDE 296  // A_sh row stride (bf16); 592B -> rotated banks, <=2-way
#define WDSTR 264    // WdT_sh row stride
#define NBLK 256     // persistent blocks (1 per CU)
#define TILES (BATCH / ROWS / NBLK)  // 8 tiles per block

__device__ __forceinline__ unsigned short f2bf(float f) {
  __hip_bfloat16 h = __float2bfloat16(f);  // RTNE
  return __builtin_bit_cast(unsigned short, h);
}

// U [256][1024] f32 -> Ut [1024][288] bf16 rows k=0..255 (transposed, k-contiguous)
__global__ __launch_bounds__(256) void k_prep(const float* __restrict__ U,
                                              unsigned short* __restrict__ Ut) {
  __shared__ float t[32][33];
  const int bk = blockIdx.x >> 5;
  const int bn = blockIdx.x & 31;
  const int r = threadIdx.x >> 5;
  const int c = threadIdx.x & 31;
#pragma unroll
  for (int i = 0; i < 4; ++i)
    t[r + 8 * i][c] = U[(size_t)(bk * 32 + r + 8 * i) * NZ + bn * 32 + c];
  __syncthreads();
#pragma unroll
  for (int i = 0; i < 4; ++i)
    Ut[(size_t)(bn * 32 + r + 8 * i) * KTOT + bk * 32 + c] = f2bf(t[c][r + 8 * i]);
}

// Ut k-rows 256..287: [W (5 rows); zeros (27 rows)] transposed.
__global__ __launch_bounds__(1024) void k_prepx(const float* __restrict__ W,
                                                unsigned short* __restrict__ Ut) {
  const int idx = blockIdx.x * 1024 + threadIdx.x;  // 32768
  const int n = idx >> 5;
  const int cc = idx & 31;
  Ut[(size_t)n * KTOT + 256 + cc] = (cc < FEAT) ? f2bf(W[(size_t)cc * NZ + n]) : (unsigned short)0;
}

// Persistent: 256 blocks x 8 tiles, double-buffered A tile in LDS.
// 1024 threads = 16 waves; wave w owns gate-col jcol = w*16+lrow for all 4 gates.
__global__ __launch_bounds__(1024, 4) void k_lstm(
    const float* __restrict__ x,    // [B][5]
    const float* __restrict__ h0,   // [B][256]
    const float* __restrict__ c0,   // [B][256]
    const float* __restrict__ b,    // [1024]
    const float* __restrict__ Wd,   // [256][5]
    const float* __restrict__ bd,   // [5]
    const unsigned short* __restrict__ Ut,  // [1024][288] bf16
    float* __restrict__ out) {
  float* out_logits = out;
  float* out_h = out + (size_t)BATCH * FEAT;
  float* out_c = out_h + (size_t)BATCH * NL;

  __shared__ __align__(16) unsigned short A_sh[2][ROWS * ASTRIDE];  // 2 x 18.9 KB
  __shared__ __align__(16) unsigned short WdT_sh[16 * WDSTR];       // 8.25 KB

  const int tid = threadIdx.x;
  const int w = tid >> 6;  // wave 0..15
  const int l = tid & 63;
  const int lrow = l & 15;
  const int lk8 = (l >> 4) * 8;
  const int lq = (l >> 4) * 4;
  const int jcol = w * 16 + lrow;  // gate col 0..255

  // ---- persistent setup (paid once): WdT, biases, B pointers
#pragma unroll
  for (int e = 0; e < 4; ++e) {
    const int idx = e * 1024 + tid;
    const int p = idx >> 8, j = idx & 255;
    WdT_sh[p * WDSTR + j] = (p < FEAT) ? f2bf(Wd[(size_t)j * FEAT + p]) : (unsigned short)0;
  }
  float bb[4];
#pragma unroll
  for (int g = 0; g < 4; ++g) bb[g] = b[g * 256 + jcol];
  float bdv = 0.f;
  if (w < 2 && lrow < FEAT) bdv = bd[lrow];

  const unsigned short* bp[4];
#pragma unroll
  for (int g = 0; g < 4; ++g) bp[g] = Ut + (size_t)(g * 256 + jcol) * KTOT + lk8;

  // staging index helpers (fixed per thread)
  const int r0 = tid >> 6, c40 = tid & 63;
  const int r1 = (1024 + tid) >> 6, c41 = tid & 63;  // second half: rows 16..31
  const int xr = tid >> 5, xc = tid & 31;

  // ---- prologue: stage tile 0 into buf 0
  {
    const int m0 = blockIdx.x * ROWS;
    const float4 v0 = *reinterpret_cast<const float4*>(h0 + (size_t)(m0 + r0) * NL + c40 * 4);
    const float4 v1 = *reinterpret_cast<const float4*>(h0 + (size_t)(m0 + r1) * NL + c41 * 4);
    float sx = 0.f;
    if (xc < FEAT) sx = x[(size_t)(m0 + xr) * FEAT + xc];
    *reinterpret_cast<ushort4*>(&A_sh[0][r0 * ASTRIDE + c40 * 4]) =
        make_ushort4(f2bf(v0.x), f2bf(v0.y), f2bf(v0.z), f2bf(v0.w));
    *reinterpret_cast<ushort4*>(&A_sh[0][r1 * ASTRIDE + c41 * 4]) =
        make_ushort4(f2bf(v1.x), f2bf(v1.y), f2bf(v1.z), f2bf(v1.w));
    A_sh[0][xr * ASTRIDE + 256 + xc] = f2bf(sx);
  }
  __syncthreads();

  bf16x8 bbuf[3][4];
#pragma unroll
  for (int g = 0; g < 4; ++g) bbuf[0][g] = *reinterpret_cast<const bf16x8*>(bp[g]);
#pragma unroll
  for (int g = 0; g < 4; ++g) bbuf[1][g] = *reinterpret_cast<const bf16x8*>(bp[g] + 32);

#pragma unroll 1
  for (int it = 0; it < TILES; ++it) {
    const int p = it & 1;
    const unsigned short* Ab = &A_sh[p][0];
    const int m0c = (it * NBLK + blockIdx.x) * ROWS;

    // c0 loads for this tile — land during k-loop
    float c0v[2][4];
#pragma unroll
    for (int r = 0; r < 2; ++r)
#pragma unroll
      for (int v = 0; v < 4; ++v)
        c0v[r][v] = c0[(size_t)(m0c + r * 16 + lq + v) * NL + jcol];

    // stage loads for next tile — land during k-loop
    float4 sv0 = {0.f, 0.f, 0.f, 0.f}, sv1 = {0.f, 0.f, 0.f, 0.f};
    float sx = 0.f;
    if (it + 1 < TILES) {
      const int m0n = ((it + 1) * NBLK + blockIdx.x) * ROWS;
      sv0 = *reinterpret_cast<const float4*>(h0 + (size_t)(m0n + r0) * NL + c40 * 4);
      sv1 = *reinterpret_cast<const float4*>(h0 + (size_t)(m0n + r1) * NL + c41 * 4);
      if (xc < FEAT) sx = x[(size_t)(m0n + xr) * FEAT + xc];
    }

    f32x4 acc[2][4];
#pragma unroll
    for (int r = 0; r < 2; ++r)
#pragma unroll
      for (int g = 0; g < 4; ++g) acc[r][g] = (f32x4){0.f, 0.f, 0.f, 0.f};

#pragma unroll
    for (int kk = 0; kk < 9; ++kk) {
      if (kk < 7) {
#pragma unroll
        for (int g = 0; g < 4; ++g)
          bbuf[(kk + 2) % 3][g] =
              *reinterpret_cast<const bf16x8*>(bp[g] + (kk + 2) * 32);
      }
      const bf16x8 af0 =
          *reinterpret_cast<const bf16x8*>(&Ab[lrow * ASTRIDE + kk * 32 + lk8]);
      const bf16x8 af1 =
          *reinterpret_cast<const bf16x8*>(&Ab[(16 + lrow) * ASTRIDE + kk * 32 + lk8]);
#pragma unroll
      for (int g = 0; g < 4; ++g) {
        acc[0][g] = __builtin_amdgcn_mfma_f32_16x16x32_bf16(af0, bbuf[kk % 3][g], acc[0][g], 0, 0, 0);
        acc[1][g] = __builtin_amdgcn_mfma_f32_16x16x32_bf16(af1, bbuf[kk % 3][g], acc[1][g], 0, 0, 0);
      }
    }

    __syncthreads();  // B1: all reads of buf[p] done; stage/c0 loads landed

    // next-tile B prefetch (tile-invariant addresses); consumer = next k-loop
#pragma unroll
    for (int g = 0; g < 4; ++g) bbuf[0][g] = *reinterpret_cast<const bf16x8*>(bp[g]);
#pragma unroll
    for (int g = 0; g < 4; ++g) bbuf[1][g] = *reinterpret_cast<const bf16x8*>(bp[g] + 32);

    // stage-writes next tile -> buf[p^1] (was last read in tile it-1)
    if (it + 1 < TILES) {
      unsigned short* Aw = &A_sh[p ^ 1][0];
      *reinterpret_cast<ushort4*>(&Aw[r0 * ASTRIDE + c40 * 4]) =
          make_ushort4(f2bf(sv0.x), f2bf(sv0.y), f2bf(sv0.z), f2bf(sv0.w));
      *reinterpret_cast<ushort4*>(&Aw[r1 * ASTRIDE + c41 * 4]) =
          make_ushort4(f2bf(sv1.x), f2bf(sv1.y), f2bf(sv1.z), f2bf(sv1.w));
      Aw[xr * ASTRIDE + 256 + xc] = f2bf(sx);
    }

    // gates -> regs; h -> LDS buf[p] (A data dead after B1)
    float cvs[2][4], hvs[2][4];
    unsigned short* Ah = &A_sh[p][0];
#pragma unroll
    for (int r = 0; r < 2; ++r) {
#pragma unroll
      for (int v = 0; v < 4; ++v) {
        const float zi = acc[r][0][v] + bb[0];
        const float zf = acc[r][1][v] + bb[1];
        const float zc = acc[r][2][v] + bb[2];
        const float zo = acc[r][3][v] + bb[3];
        const float ig = 1.f / (1.f + __expf(-zi));
        const float fg = 1.f / (1.f + __expf(-zf));
        const float og = 1.f / (1.f + __expf(-zo));
        const float rc = fmaxf(zc, 0.f);
        const float cv = fg * c0v[r][v] + ig * rc;
        const float hv = og * fmaxf(cv, 0.f);
        cvs[r][v] = cv;
        hvs[r][v] = hv;
        Ah[(r * 16 + lq + v) * ASTRIDE + jcol] = f2bf(hv);
      }
    }

    __syncthreads();  // B2: h visible; stage-writes to buf[p^1] visible

    // global stores after B2 -> vmcnt drains under NEXT k-loop
#pragma unroll
    for (int r = 0; r < 2; ++r)
#pragma unroll
      for (int v = 0; v < 4; ++v) {
        const size_t m = (size_t)m0c + r * 16 + lq + v;
        out_c[m * NL + jcol] = cvs[r][v];
        out_h[m * NL + jcol] = hvs[r][v];
      }

    // logits tail (waves 0,1) overlaps next tile's k-loop on other waves
    if (w < 2) {
      f32x4 lacc = (f32x4){0.f, 0.f, 0.f, 0.f};
#pragma unroll
      for (int kk = 0; kk < 8; ++kk) {
        const bf16x8 ah = *reinterpret_cast<const bf16x8*>(
            &A_sh[p][(w * 16 + lrow) * ASTRIDE + kk * 32 + lk8]);
        const bf16x8 bw = *reinterpret_cast<const bf16x8*>(
            &WdT_sh[lrow * WDSTR + kk * 32 + lk8]);
        lacc = __builtin_amdgcn_mfma_f32_16x16x32_bf16(ah, bw, lacc, 0, 0, 0);
      }
      if (lrow < FEAT) {
#pragma unroll
        for (int v = 0; v < 4; ++v)
          out_logits[(size_t)(m0c + w * 16 + lq + v) * FEAT + lrow] = lacc[v] + bdv;
      }
    }
  }
}

extern "C" void kernel_launch(void* const* d_in, const int* in_sizes, int n_in,
                              void* d_out, int out_size, void* d_ws, size_t ws_size,
                              hipStream_t stream) {
  const float* x = (const float*)d_in[0];   // seq_in [65536][1][5]
  const float* h0 = (const float*)d_in[1];  // [65536][256]
  const float* c0 = (const float*)d_in[2];  // [65536][256]
  const float* W = (const float*)d_in[3];   // [5][1024]
  const float* U = (const float*)d_in[4];   // [256][1024]
  const float* b = (const float*)d_in[5];   // [1024]
  const float* Wd = (const float*)d_in[6];  // [256][5]
  const float* bd = (const float*)d_in[7];  // [5]
  unsigned short* Ut = (unsigned short*)d_ws;  // 1024*288*2 = 576 KB

  k_prep<<<256, 256, 0, stream>>>(U, Ut);
  k_prepx<<<32, 1024, 0, stream>>>(W, Ut);
  k_lstm<<<NBLK, 1024, 0, stream>>>(x, h0, c0, b, Wd, bd, Ut, (float*)d_out);
}

// Round 6
// 134.366 us; speedup vs baseline: 1.7423x; 1.7423x over previous
//
#include <hip/hip_runtime.h>
#include <hip/hip_bf16.h>

typedef __bf16 bf16x8 __attribute__((ext_vector_type(8)));
typedef float f32x4 __attribute__((ext_vector_type(4)));

#define BATCH 65536
#define NL 256    // N_LSTM
#define NZ 1024   // 4*N_LSTM
#define FEAT 5
#define ROWS 32   // batch rows per block
#define KTOT 288  // 256 (h@U) + 32 (x@W folded: 5 real + 27 zero)
#define ASTRIDE 296  // A_sh row stride (bf16); 592B -> rotated banks, <=2-way
#define WDSTR 264    // WdT_sh row stride

__device__ __forceinline__ unsigned short f2bf(float f) {
  __hip_bfloat16 h = __float2bfloat16(f);  // RTNE
  return __builtin_bit_cast(unsigned short, h);
}

__device__ __forceinline__ float sigm(float z) {
  // 1/(1+2^(-z*log2e)); v_exp_f32 + v_rcp_f32, ~4 VALU
  return __builtin_amdgcn_rcpf(1.f + __builtin_amdgcn_exp2f(z * -1.4426950408889634f));
}

// U [256][1024] f32 -> Ut [1024][288] bf16 rows k=0..255 (transposed, k-contiguous)
__global__ __launch_bounds__(256) void k_prep(const float* __restrict__ U,
                                              unsigned short* __restrict__ Ut) {
  __shared__ float t[32][33];
  const int bk = blockIdx.x >> 5;
  const int bn = blockIdx.x & 31;
  const int r = threadIdx.x >> 5;
  const int c = threadIdx.x & 31;
#pragma unroll
  for (int i = 0; i < 4; ++i)
    t[r + 8 * i][c] = U[(size_t)(bk * 32 + r + 8 * i) * NZ + bn * 32 + c];
  __syncthreads();
#pragma unroll
  for (int i = 0; i < 4; ++i)
    Ut[(size_t)(bn * 32 + r + 8 * i) * KTOT + bk * 32 + c] = f2bf(t[c][r + 8 * i]);
}

// Ut k-rows 256..287: [W (5 rows); zeros (27 rows)] transposed.
__global__ __launch_bounds__(1024) void k_prepx(const float* __restrict__ W,
                                                unsigned short* __restrict__ Ut) {
  const int idx = blockIdx.x * 1024 + threadIdx.x;  // 32768
  const int n = idx >> 5;
  const int cc = idx & 31;
  Ut[(size_t)n * KTOT + 256 + cc] = (cc < FEAT) ? f2bf(W[(size_t)cc * NZ + n]) : (unsigned short)0;
}

// 1024 threads = 16 waves; wave w owns gate-col jcol = w*16+lrow for all 4 gates.
__global__ __launch_bounds__(1024, 4) void k_lstm(
    const float* __restrict__ x,    // [B][5]
    const float* __restrict__ h0,   // [B][256]
    const float* __restrict__ c0,   // [B][256]
    const float* __restrict__ b,    // [1024]
    const float* __restrict__ Wd,   // [256][5]
    const float* __restrict__ bd,   // [5]
    const unsigned short* __restrict__ Ut,  // [1024][288] bf16
    float* __restrict__ out) {
  float* out_logits = out;
  float* out_h = out + (size_t)BATCH * FEAT;
  float* out_c = out_h + (size_t)BATCH * NL;

  __shared__ __align__(16) unsigned short A_sh[ROWS * ASTRIDE];   // 18.9 KB
  __shared__ __align__(16) unsigned short WdT_sh[16 * WDSTR];     // 8.25 KB

  const int tid = threadIdx.x;
  const int w = tid >> 6;   // wave 0..15
  const int l = tid & 63;
  const int lrow = l & 15;
  const int lk8 = (l >> 4) * 8;
  const int lq = (l >> 4) * 4;
  const int m0 = blockIdx.x * ROWS;

  // ---- stage A tile: h0 [32][256] f32 -> bf16 cols 0..255
#pragma unroll
  for (int it = 0; it < 2; ++it) {
    const int fi = it * 1024 + tid;  // float4 index
    const int row = fi >> 6;
    const int c4 = fi & 63;
    const float4 v =
        *reinterpret_cast<const float4*>(h0 + (size_t)(m0 + row) * NL + c4 * 4);
    const ushort4 q = make_ushort4(f2bf(v.x), f2bf(v.y), f2bf(v.z), f2bf(v.w));
    *reinterpret_cast<ushort4*>(&A_sh[row * ASTRIDE + c4 * 4]) = q;
  }
  // x block: cols 256..287 = [x (5), zeros]
  {
    const int row = tid >> 5;
    const int cc = tid & 31;
    unsigned short v = 0;
    if (cc < FEAT) v = f2bf(x[(size_t)(m0 + row) * FEAT + cc]);
    A_sh[row * ASTRIDE + 256 + cc] = v;
  }
  // WdT_sh[p][j] = Wd[j][p], p padded 5->16 with zeros
#pragma unroll
  for (int e = 0; e < 4; ++e) {
    const int idx = e * 1024 + tid;  // 4096 entries
    const int p = idx >> 8;
    const int j = idx & 255;
    WdT_sh[p * WDSTR + j] = (p < FEAT) ? f2bf(Wd[(size_t)j * FEAT + p]) : (unsigned short)0;
  }
  __syncthreads();

  const int jcol = w * 16 + lrow;  // gate col 0..255

  float bb[4];
#pragma unroll
  for (int g = 0; g < 4; ++g) bb[g] = b[g * 256 + jcol];

  // ---- k-loop: 2-deep rotating register prefetch of B, issue order pinned
  f32x4 acc[2][4];
#pragma unroll
  for (int r = 0; r < 2; ++r)
#pragma unroll
    for (int g = 0; g < 4; ++g) acc[r][g] = (f32x4){0.f, 0.f, 0.f, 0.f};

  const unsigned short* bp[4];
#pragma unroll
  for (int g = 0; g < 4; ++g) bp[g] = Ut + (size_t)(g * 256 + jcol) * KTOT + lk8;

  bf16x8 bbuf[3][4];
#pragma unroll
  for (int g = 0; g < 4; ++g) bbuf[0][g] = *reinterpret_cast<const bf16x8*>(bp[g]);
#pragma unroll
  for (int g = 0; g < 4; ++g) bbuf[1][g] = *reinterpret_cast<const bf16x8*>(bp[g] + 32);

#pragma unroll
  for (int kk = 0; kk < 9; ++kk) {
    if (kk < 7) {
#pragma unroll
      for (int g = 0; g < 4; ++g)
        bbuf[(kk + 2) % 3][g] =
            *reinterpret_cast<const bf16x8*>(bp[g] + (kk + 2) * 32);
      // pin issue order: 4 B prefetch loads FIRST
      __builtin_amdgcn_sched_group_barrier(0x20, 4, 0);  // VMEM_READ x4
    }
    const bf16x8 af0 =
        *reinterpret_cast<const bf16x8*>(&A_sh[lrow * ASTRIDE + kk * 32 + lk8]);
    const bf16x8 af1 =
        *reinterpret_cast<const bf16x8*>(&A_sh[(16 + lrow) * ASTRIDE + kk * 32 + lk8]);
    __builtin_amdgcn_sched_group_barrier(0x100, 2, 0);   // DS_READ x2
#pragma unroll
    for (int g = 0; g < 4; ++g) {
      acc[0][g] = __builtin_amdgcn_mfma_f32_16x16x32_bf16(af0, bbuf[kk % 3][g], acc[0][g], 0, 0, 0);
      acc[1][g] = __builtin_amdgcn_mfma_f32_16x16x32_bf16(af1, bbuf[kk % 3][g], acc[1][g], 0, 0, 0);
    }
    __builtin_amdgcn_sched_group_barrier(0x8, 8, 0);     // MFMA x8
  }

  // c0 loads issued here: latency hides under barrier drain + gate math below
  float c0v[2][4];
#pragma unroll
  for (int r = 0; r < 2; ++r)
#pragma unroll
    for (int v = 0; v < 4; ++v)
      c0v[r][v] = c0[(size_t)(m0 + r * 16 + lq + v) * NL + jcol];

  __syncthreads();  // B1: all k-loop A_sh reads done before h overwrites

  // ---- epilogue: gates, c/h stores, h -> A_sh (bf16) for logits MFMA
#pragma unroll
  for (int r = 0; r < 2; ++r) {
#pragma unroll
    for (int v = 0; v < 4; ++v) {
      const int mloc = r * 16 + lq + v;
      const size_t m = (size_t)m0 + mloc;
      const float zi = acc[r][0][v] + bb[0];
      const float zf = acc[r][1][v] + bb[1];
      const float zc = acc[r][2][v] + bb[2];
      const float zo = acc[r][3][v] + bb[3];
      const float ig = sigm(zi);
      const float fg = sigm(zf);
      const float og = sigm(zo);
      const float rc = fmaxf(zc, 0.f);
      const float cv = fg * c0v[r][v] + ig * rc;
      const float hv = og * fmaxf(cv, 0.f);
      out_c[m * NL + jcol] = cv;
      out_h[m * NL + jcol] = hv;
      A_sh[mloc * ASTRIDE + jcol] = f2bf(hv);
    }
  }
  __syncthreads();

  // ---- logits = h @ Wd + bd via MFMA: waves 0,1 only; 8 chained MFMAs each
  if (w < 2) {
    f32x4 lacc = (f32x4){0.f, 0.f, 0.f, 0.f};
#pragma unroll
    for (int kk = 0; kk < 8; ++kk) {
      const bf16x8 ah = *reinterpret_cast<const bf16x8*>(
          &A_sh[(w * 16 + lrow) * ASTRIDE + kk * 32 + lk8]);
      const bf16x8 bw = *reinterpret_cast<const bf16x8*>(
          &WdT_sh[lrow * WDSTR + kk * 32 + lk8]);
      lacc = __builtin_amdgcn_mfma_f32_16x16x32_bf16(ah, bw, lacc, 0, 0, 0);
    }
    if (lrow < FEAT) {
      const float bdv = bd[lrow];
#pragma unroll
      for (int v = 0; v < 4; ++v)
        out_logits[(size_t)(m0 + w * 16 + lq + v) * FEAT + lrow] = lacc[v] + bdv;
    }
  }
}

extern "C" void kernel_launch(void* const* d_in, const int* in_sizes, int n_in,
                              void* d_out, int out_size, void* d_ws, size_t ws_size,
                              hipStream_t stream) {
  const float* x = (const float*)d_in[0];   // seq_in [65536][1][5]
  const float* h0 = (const float*)d_in[1];  // [65536][256]
  const float* c0 = (const float*)d_in[2];  // [65536][256]
  const float* W = (const float*)d_in[3];   // [5][1024]
  const float* U = (const float*)d_in[4];   // [256][1024]
  const float* b = (const float*)d_in[5];   // [1024]
  const float* Wd = (const float*)d_in[6];  // [256][5]
  const float* bd = (const float*)d_in[7];  // [5]
  unsigned short* Ut = (unsigned short*)d_ws;  // 1024*288*2 = 576 KB

  k_prep<<<256, 256, 0, stream>>>(U, Ut);
  k_prepx<<<32, 1024, 0, stream>>>(W, Ut);
  k_lstm<<<BATCH / ROWS, 1024, 0, stream>>>(x, h0, c0, b, Wd, bd, Ut, (float*)d_out);
}